// Round 10
// baseline (243.790 us; speedup 1.0000x reference)
//
#include <hip/hip_runtime.h>

#define SEQ  2048
#define DIM  1024
#define NTOK 8192   // 4*SEQ
#define NQKV 3072

typedef __attribute__((ext_vector_type(8))) __bf16 bf16x8;
typedef __attribute__((ext_vector_type(4))) float  f32x4;

__device__ __forceinline__ unsigned short f2bf(float f) {
    unsigned int u = __float_as_uint(f);
    u += 0x7fffu + ((u >> 16) & 1u);          // round-to-nearest-even
    return (unsigned short)(u >> 16);
}

__device__ __forceinline__ float bfu2f(unsigned int lo16) {
    return __uint_as_float(lo16 << 16);
}

__device__ __forceinline__ void load_lds_128(const unsigned short* g, unsigned short* l) {
    __builtin_amdgcn_global_load_lds(
        (const __attribute__((address_space(1))) void*)g,
        (__attribute__((address_space(3))) void*)l, 16, 0, 0);
}

#define BAR() asm volatile("s_barrier" ::: "memory")

// ---------------------------------------------------------------------------
// r3-form K-loop (best measured: 65.5-66.0 us across QKV/QK/PV when compiled
// in the r7 instantiation set).  NT GEMM, bf16 MFMA 16x16x32, 256x128 block,
// BK=64, 8 waves 4M x 2N (64x64/wave, acc[4][4]).  3-slot LDS ring,
// distance-2 prefetch, counted vmcnt(6), ONE barrier per K-tile, register
// fragment double-buffer (counted lgkmcnt overlap).  kk0/kk1 separate.
//
// LDS rows 128B; slot c of row r holds global chunk g = c ^ (r&7) ->
// ds_read_b128 2-way (free); SQ_LDS_BANK_CONFLICT==0 verified r2-r9.
//
// rule-#19 lesson (r9): adding a third MODE instantiation to this template
// perturbed codegen of ALL modes (66 -> 75.5 us, same VGPR/LDS/FETCH).
// This template must compile with EXACTLY MODE 0 and MODE 2 (r7 layout);
// PV lives in the standalone gemm_pv below.  Do not re-merge.
//
// r8 lesson: no XCD swizzle here — 1-D chunked swizzle quadrupled FETCH
// (48.8 -> 199.7 MB) and cost +20 us/GEMM.  Default dispatch is near-ideal.
//
// MODE 0: fused QKV epilogue (q,k bf16 + bias; v transposed into vt + bias)
// MODE 2: bf16 P = exp(acc*alpha) + fused row-sum (atomicAdd of bf16-rounded
//         partials into rs[row])
// ---------------------------------------------------------------------------
template <int MODE>
__global__ __launch_bounds__(512, 2)
void gemm256(const unsigned short* __restrict__ A, const unsigned short* __restrict__ B,
             void* __restrict__ Cv,
             const float* __restrict__ b0v, const float* __restrict__ b1v,
             const float* __restrict__ b2v, unsigned short* __restrict__ vt,
             float* __restrict__ rsv,
             int K, int lda, int ldb, int ldc,
             long sA, long sB, long sC, float alpha)
{
    constexpr int AT = 256 * 64;               // elems per A slot (32 KB)
    constexpr int BT = 128 * 64;               // elems per B slot (16 KB)
    __shared__ __align__(16) unsigned short As[3 * AT];   // 96 KB
    __shared__ __align__(16) unsigned short Bs[3 * BT];   // 48 KB

    const int tid  = threadIdx.x;              // 512 threads = 8 waves
    const int wave = tid >> 6;
    const int lane = tid & 63;
    const int l4   = lane & 15;
    const int lh   = lane >> 4;
    const int wm   = wave >> 1;                // 0..3  (M quarter)
    const int wn   = wave & 1;                 // 0..1  (N half)

    const int m0 = blockIdx.x * 256;
    const int n0 = blockIdx.y * 128;
    const int z  = blockIdx.z;
    A += (long)z * sA;
    B += (long)z * sB;

    const int r0 = tid >> 3;                   // 0..63
    const int gc = (tid & 7) ^ (r0 & 7);
    const unsigned short* Ag = A + (long)(m0 + r0) * lda + gc * 8;
    const unsigned short* Bg = B + (long)(n0 + r0) * ldb + gc * 8;
    unsigned short* Al = As + tid * 8;
    unsigned short* Bl = Bs + tid * 8;

    const int NT = K >> 6;                     // K-tiles of 64

    auto stage = [&](int t, int slot, int ph) {
        const long kof = (long)t * 64;
        unsigned short* al = Al + slot * AT;
        unsigned short* bl = Bl + slot * BT;
        if (ph == 0) {
            load_lds_128(Ag + kof,                          al);
            load_lds_128(Ag + kof + (long)64 * lda,         al + 4096);
            load_lds_128(Bg + kof,                          bl);
        } else {
            load_lds_128(Ag + kof + (long)128 * lda,        al + 8192);
            load_lds_128(Ag + kof + (long)192 * lda,        al + 12288);
            load_lds_128(Bg + kof + (long)64 * ldb,         bl + 4096);
        }
    };

    const int aoff = (wm * 64 + l4) * 64;      // + mf*1024 + cs[kk]
    const int boff = (wn * 64 + l4) * 64;      // + nf*1024 + cs[kk]
    const int cs0  = ((0 + lh) ^ (lane & 7)) * 8;
    const int cs1  = ((4 + lh) ^ (lane & 7)) * 8;

    f32x4 acc[4][4] = {};
    bf16x8 a0[4], b0[4], a1[4], b1[4];

    auto ldfrag = [&](bf16x8 (&a)[4], bf16x8 (&b)[4],
                      const unsigned short* Ab, const unsigned short* Bb, int cs) {
#pragma unroll
        for (int mf = 0; mf < 4; ++mf) a[mf] = *(const bf16x8*)(Ab + mf * 1024 + cs);
#pragma unroll
        for (int nf = 0; nf < 4; ++nf) b[nf] = *(const bf16x8*)(Bb + nf * 1024 + cs);
    };
    auto mfma16 = [&](bf16x8 (&a)[4], bf16x8 (&b)[4]) {
        __builtin_amdgcn_s_setprio(1);
#pragma unroll
        for (int mf = 0; mf < 4; ++mf)
#pragma unroll
            for (int nf = 0; nf < 4; ++nf)
                acc[mf][nf] = __builtin_amdgcn_mfma_f32_16x16x32_bf16(
                    a[mf], b[nf], acc[mf][nf], 0, 0, 0);
        __builtin_amdgcn_s_setprio(0);
    };

    // prologue: stage tiles 0,1; drain tile 0 (stage(1) stays in flight)
    stage(0, 0, 0); stage(0, 0, 1);
    stage(1, 1, 0); stage(1, 1, 1);
    asm volatile("s_waitcnt vmcnt(6)" ::: "memory");
    BAR();
    ldfrag(a0, b0, As + aoff, Bs + boff, cs0);   // tile 0, kk=0

    int sl = 0;
    for (int t = 0; t < NT; ++t) {
        const unsigned short* Ab = As + sl * AT + aoff;
        const unsigned short* Bb = Bs + sl * BT + boff;
        const int st  = (sl >= 1) ? sl - 1 : 2;        // (sl+2)%3
        const int nsl = (sl == 2) ? 0 : sl + 1;

        // phase A: issue rd(t,kk1), stage, MFMA on (t,kk0)
        ldfrag(a1, b1, Ab, Bb, cs1);
        if (t + 2 < NT) stage(t + 2, st, 0);
        mfma16(a0, b0);                 // counted lgkmcnt: a1/b1 in flight

        // phase B: stage, drain+barrier, rd(t+1,kk0), MFMA (t,kk1)
        if (t + 2 < NT) stage(t + 2, st, 1);
        asm volatile("s_waitcnt lgkmcnt(0)" ::: "memory");   // WAR invariant
        if (t < NT - 2) asm volatile("s_waitcnt vmcnt(6)" ::: "memory");
        else            asm volatile("s_waitcnt vmcnt(0)" ::: "memory");
        BAR();
        if (t + 1 < NT)
            ldfrag(a0, b0, As + nsl * AT + aoff, Bs + nsl * BT + boff, cs0);
        mfma16(a1, b1);
        sl = nsl;
    }

    // ---- epilogue ----
    // C/D 16x16x32: col = lane&15 (+nf*16), row = (lane>>4)*4 + reg (+mf*16)
    const int r0c = m0 + wm * 64 + lh * 4;
    const int c0c = n0 + wn * 64 + l4;

    if (MODE == 0) {
        if (n0 >= 2048) {
#pragma unroll
            for (int nf = 0; nf < 4; ++nf) {
                const int d = c0c + nf * 16 - 2048;
                const float bias = b2v[d];
#pragma unroll
                for (int mf = 0; mf < 4; ++mf) {
                    const int row = r0c + mf * 16;
                    const int bb = row >> 11;
                    const int mm = row & 2047;
                    ushort4 u;
                    u.x = f2bf(acc[mf][nf][0] + bias);
                    u.y = f2bf(acc[mf][nf][1] + bias);
                    u.z = f2bf(acc[mf][nf][2] + bias);
                    u.w = f2bf(acc[mf][nf][3] + bias);
                    *(ushort4*)(vt + ((long)bb * DIM + d) * SEQ + mm) = u;
                }
            }
        } else {
            unsigned short* C16 = (unsigned short*)Cv;
#pragma unroll
            for (int nf = 0; nf < 4; ++nf) {
                const int col = c0c + nf * 16;
                const float bias = (col >= 1024) ? b1v[col - 1024] : b0v[col];
#pragma unroll
                for (int mf = 0; mf < 4; ++mf)
#pragma unroll
                    for (int r = 0; r < 4; ++r)
                        C16[(long)(r0c + mf * 16 + r) * ldc + col] =
                            f2bf(acc[mf][nf][r] + bias);
            }
        }
    } else {  // MODE 2: P = exp(acc*alpha) bf16 + fused row-sum atomics
        unsigned short* C16 = (unsigned short*)Cv + (long)z * sC;
        float* rs = rsv + (long)z * SEQ;
#pragma unroll
        for (int mf = 0; mf < 4; ++mf)
#pragma unroll
            for (int r = 0; r < 4; ++r) {
                const int rowi = r0c + mf * 16 + r;
                float s = 0.f;
#pragma unroll
                for (int nf = 0; nf < 4; ++nf) {
                    const int col = c0c + nf * 16;
                    const unsigned short pu = f2bf(__expf(acc[mf][nf][r] * alpha));
                    C16[(long)rowi * ldc + col] = pu;
                    s += bfu2f(pu);            // sum the ROUNDED value
                }
                // reduce over the 16-lane l4 group (same lh -> same rows)
                s += __shfl_xor(s, 1);
                s += __shfl_xor(s, 2);
                s += __shfl_xor(s, 4);
                s += __shfl_xor(s, 8);
                if (l4 == 0) atomicAdd(rs + rowi, s);
            }
    }
}

// ---------------------------------------------------------------------------
// Standalone PV kernel: identical r3-form loop, independent codegen (NOT a
// gemm256 instantiation — rule #19).  C = (P . vt^T) / rs[row], fp32.
// A = P bf16 [z][2048][2048] (lda 2048), B = vt bf16 [z][1024][2048]
// (ldb 2048), K = 2048.  Grid 8x8x4 = 256 blocks.
// ---------------------------------------------------------------------------
__global__ __launch_bounds__(512, 2)
void gemm_pv(const unsigned short* __restrict__ A, const unsigned short* __restrict__ B,
             float* __restrict__ C, const float* __restrict__ rsv,
             int K, int lda, int ldb, int ldc,
             long sA, long sB, long sC)
{
    constexpr int AT = 256 * 64;
    constexpr int BT = 128 * 64;
    __shared__ __align__(16) unsigned short As[3 * AT];   // 96 KB
    __shared__ __align__(16) unsigned short Bs[3 * BT];   // 48 KB

    const int tid  = threadIdx.x;
    const int wave = tid >> 6;
    const int lane = tid & 63;
    const int l4   = lane & 15;
    const int lh   = lane >> 4;
    const int wm   = wave >> 1;
    const int wn   = wave & 1;

    const int m0 = blockIdx.x * 256;
    const int n0 = blockIdx.y * 128;
    const int z  = blockIdx.z;
    A += (long)z * sA;
    B += (long)z * sB;

    const int r0 = tid >> 3;
    const int gc = (tid & 7) ^ (r0 & 7);
    const unsigned short* Ag = A + (long)(m0 + r0) * lda + gc * 8;
    const unsigned short* Bg = B + (long)(n0 + r0) * ldb + gc * 8;
    unsigned short* Al = As + tid * 8;
    unsigned short* Bl = Bs + tid * 8;

    const int NT = K >> 6;

    auto stage = [&](int t, int slot, int ph) {
        const long kof = (long)t * 64;
        unsigned short* al = Al + slot * AT;
        unsigned short* bl = Bl + slot * BT;
        if (ph == 0) {
            load_lds_128(Ag + kof,                          al);
            load_lds_128(Ag + kof + (long)64 * lda,         al + 4096);
            load_lds_128(Bg + kof,                          bl);
        } else {
            load_lds_128(Ag + kof + (long)128 * lda,        al + 8192);
            load_lds_128(Ag + kof + (long)192 * lda,        al + 12288);
            load_lds_128(Bg + kof + (long)64 * ldb,         bl + 4096);
        }
    };

    const int aoff = (wm * 64 + l4) * 64;
    const int boff = (wn * 64 + l4) * 64;
    const int cs0  = ((0 + lh) ^ (lane & 7)) * 8;
    const int cs1  = ((4 + lh) ^ (lane & 7)) * 8;

    f32x4 acc[4][4] = {};
    bf16x8 a0[4], b0[4], a1[4], b1[4];

    auto ldfrag = [&](bf16x8 (&a)[4], bf16x8 (&b)[4],
                      const unsigned short* Ab, const unsigned short* Bb, int cs) {
#pragma unroll
        for (int mf = 0; mf < 4; ++mf) a[mf] = *(const bf16x8*)(Ab + mf * 1024 + cs);
#pragma unroll
        for (int nf = 0; nf < 4; ++nf) b[nf] = *(const bf16x8*)(Bb + nf * 1024 + cs);
    };
    auto mfma16 = [&](bf16x8 (&a)[4], bf16x8 (&b)[4]) {
        __builtin_amdgcn_s_setprio(1);
#pragma unroll
        for (int mf = 0; mf < 4; ++mf)
#pragma unroll
            for (int nf = 0; nf < 4; ++nf)
                acc[mf][nf] = __builtin_amdgcn_mfma_f32_16x16x32_bf16(
                    a[mf], b[nf], acc[mf][nf], 0, 0, 0);
        __builtin_amdgcn_s_setprio(0);
    };

    stage(0, 0, 0); stage(0, 0, 1);
    stage(1, 1, 0); stage(1, 1, 1);
    asm volatile("s_waitcnt vmcnt(6)" ::: "memory");
    BAR();
    ldfrag(a0, b0, As + aoff, Bs + boff, cs0);

    int sl = 0;
    for (int t = 0; t < NT; ++t) {
        const unsigned short* Ab = As + sl * AT + aoff;
        const unsigned short* Bb = Bs + sl * BT + boff;
        const int st  = (sl >= 1) ? sl - 1 : 2;
        const int nsl = (sl == 2) ? 0 : sl + 1;

        ldfrag(a1, b1, Ab, Bb, cs1);
        if (t + 2 < NT) stage(t + 2, st, 0);
        mfma16(a0, b0);

        if (t + 2 < NT) stage(t + 2, st, 1);
        asm volatile("s_waitcnt lgkmcnt(0)" ::: "memory");
        if (t < NT - 2) asm volatile("s_waitcnt vmcnt(6)" ::: "memory");
        else            asm volatile("s_waitcnt vmcnt(0)" ::: "memory");
        BAR();
        if (t + 1 < NT)
            ldfrag(a0, b0, As + nsl * AT + aoff, Bs + nsl * BT + boff, cs0);
        mfma16(a1, b1);
        sl = nsl;
    }

    // epilogue: C = acc / rs[row]
    float* Cz = C + (long)z * sC;
    const float* rsp = rsv + (long)z * SEQ;
    const int r0c = m0 + wm * 64 + lh * 4;
    const int c0c = n0 + wn * 64 + l4;
#pragma unroll
    for (int mf = 0; mf < 4; ++mf) {
        const int rowb = r0c + mf * 16;
        const float4 rs4 = *(const float4*)(rsp + rowb);
        const float i0 = 1.0f / rs4.x, i1 = 1.0f / rs4.y;
        const float i2 = 1.0f / rs4.z, i3 = 1.0f / rs4.w;
#pragma unroll
        for (int nf = 0; nf < 4; ++nf) {
            const int col = c0c + nf * 16;
            Cz[(long)(rowb + 0) * ldc + col] = acc[mf][nf][0] * i0;
            Cz[(long)(rowb + 1) * ldc + col] = acc[mf][nf][1] * i1;
            Cz[(long)(rowb + 2) * ldc + col] = acc[mf][nf][2] * i2;
            Cz[(long)(rowb + 3) * ldc + col] = acc[mf][nf][3] * i3;
        }
    }
}

// ---------------------------------------------------------------------------
// Merged preprocessing (1 dispatch): x->bf16, W{q,k,v}->bf16, rs zero.
// ---------------------------------------------------------------------------
#define PREP_BLOCKS (8192 + 3072 + 32)

__global__ __launch_bounds__(256)
void prep(const float* __restrict__ x,
          const float* __restrict__ Wq, const float* __restrict__ Wk,
          const float* __restrict__ Wv,
          unsigned short* __restrict__ xb, unsigned short* __restrict__ Wb,
          float* __restrict__ rs)
{
    const int b = blockIdx.x;
    if (b < 8192) {
        const int i = b * 256 + threadIdx.x;
        float4 f = ((const float4*)x)[i];
        ushort4 u;
        u.x = f2bf(f.x); u.y = f2bf(f.y); u.z = f2bf(f.z); u.w = f2bf(f.w);
        ((ushort4*)xb)[i] = u;
    } else if (b < 8192 + 3072) {
        const int idx = (b - 8192) * 256 + threadIdx.x;   // 0 .. 786431
        const int sel = idx / (DIM * DIM / 4);
        const int j   = idx - sel * (DIM * DIM / 4);
        const float* src = (sel == 0) ? Wq : ((sel == 1) ? Wk : Wv);
        float4 f = ((const float4*)src)[j];
        ushort4 u;
        u.x = f2bf(f.x); u.y = f2bf(f.y); u.z = f2bf(f.z); u.w = f2bf(f.w);
        ((ushort4*)(Wb + (long)sel * DIM * DIM))[j] = u;
    } else {
        const int idx = (b - 8192 - 3072) * 256 + threadIdx.x;
        if (idx < NTOK) rs[idx] = 0.f;
    }
}

// ---------------------------------------------------------------------------
extern "C" void kernel_launch(void* const* d_in, const int* in_sizes, int n_in,
                              void* d_out, int out_size, void* d_ws, size_t ws_size,
                              hipStream_t stream)
{
    const float* x  = (const float*)d_in[0];
    const float* Wq = (const float*)d_in[1];
    const float* bq = (const float*)d_in[2];
    const float* Wk = (const float*)d_in[3];
    const float* bk = (const float*)d_in[4];
    const float* Wv = (const float*)d_in[5];
    const float* bv = (const float*)d_in[6];
    float* out = (float*)d_out;

    // Workspace layout (>=160MB + 32KB):
    //  [0,16MB):    xb bf16 [8192][1024]
    //  [16,22MB):   Wb bf16 [3][1024][1024]
    //  [64,112MB):  qkv bf16 [8192][3072]  (V cols never written; vt instead)
    //  [112,128MB): vt  bf16 [4][1024][2048]
    //  [128,160MB): P   bf16 [4][2048][2048]  (unnormalized exp)
    //  [160MB,+32KB): rs fp32 [8192]  (row sums, atomic-accumulated)
    char* ws = (char*)d_ws;
    unsigned short* xb   = (unsigned short*)ws;
    unsigned short* Wb   = (unsigned short*)(ws + 16u * 1024 * 1024);
    unsigned short* qkv  = (unsigned short*)(ws + 64u * 1024 * 1024);
    unsigned short* vt   = (unsigned short*)(ws + 112u * 1024 * 1024);
    unsigned short* P    = (unsigned short*)(ws + 128u * 1024 * 1024);
    float*          rs   = (float*)(ws + 160u * 1024 * 1024);

    const float scale = 0.03125f;   // 1/sqrt(1024)
    dim3 blk512(512);

    // 1) merged converts + rs zero (one dispatch)
    prep<<<PREP_BLOCKS, 256, 0, stream>>>(x, Wq, Wk, Wv, xb, Wb, rs);

    // 2) fused QKV projection, 256x128 tiles -> 32*24 = 768 blocks
    gemm256<0><<<dim3(NTOK / 256, NQKV / 128), blk512, 0, stream>>>(
        xb, Wb, qkv, bq, bk, bv, vt, nullptr,
        DIM, DIM, DIM, NQKV, 0, 0, 0, 1.0f);

    // 3) P = exp(q.k^T * scale) + fused row-sum atomics; 8*16*4 = 512 blocks
    gemm256<2><<<dim3(SEQ / 256, SEQ / 128, 4), blk512, 0, stream>>>(
        qkv, qkv + 1024, P, nullptr, nullptr, nullptr, nullptr, rs,
        DIM, NQKV, NQKV, SEQ,
        (long)SEQ * NQKV, (long)SEQ * NQKV, (long)SEQ * SEQ, scale);

    // 4) out = (P.vt^T) / rs, 256x128 tiles -> 8*8*4 = 256 blocks
    gemm_pv<<<dim3(SEQ / 256, DIM / 128, 4), blk512, 0, stream>>>(
        P, vt, out, rs,
        SEQ, SEQ, SEQ, DIM,
        (long)SEQ * SEQ, (long)DIM * SEQ, (long)SEQ * DIM);
}

// Round 11
// 240.654 us; speedup vs baseline: 1.0130x; 1.0130x over previous
//
#include <hip/hip_runtime.h>

#define SEQ  2048
#define DIM  1024
#define NTOK 8192   // 4*SEQ
#define NQKV 3072

typedef __attribute__((ext_vector_type(8))) __bf16 bf16x8;
typedef __attribute__((ext_vector_type(4))) float  f32x4;

__device__ __forceinline__ unsigned short f2bf(float f) {
    unsigned int u = __float_as_uint(f);
    u += 0x7fffu + ((u >> 16) & 1u);          // round-to-nearest-even
    return (unsigned short)(u >> 16);
}

__device__ __forceinline__ float bfu2f(unsigned int lo16) {
    return __uint_as_float(lo16 << 16);
}

__device__ __forceinline__ void load_lds_128(const unsigned short* g, unsigned short* l) {
    __builtin_amdgcn_global_load_lds(
        (const __attribute__((address_space(1))) void*)g,
        (__attribute__((address_space(3))) void*)l, 16, 0, 0);
}

#define BAR() asm volatile("s_barrier" ::: "memory")

// ---------------------------------------------------------------------------
// r3-form K-loop (best measured: 64.2-66.7 us, r10).  NT GEMM, bf16 MFMA
// 16x16x32, 256x128 block, BK=64, 8 waves 4M x 2N (64x64/wave, acc[4][4]).
// 3-slot LDS ring, distance-2 prefetch, counted vmcnt(6), ONE barrier per
// K-tile, register fragment double-buffer (counted lgkmcnt overlap).
//
// LDS rows 128B; slot c of row r holds global chunk g = c ^ (r&7) ->
// ds_read_b128 2-way (free); SQ_LDS_BANK_CONFLICT==0 verified r2-r10.
//
// rule-#19 (r9/r10 measured): this template compiles with EXACTLY MODE 0
// and MODE 2; a third instantiation cost +14% on ALL modes.  PV is the
// standalone gemm_pv.  K-loop below is byte-identical to r10.  Do not merge.
// r8: no XCD swizzle (1-D chunked swizzle 4x'd FETCH, +20us/GEMM).
//
// r11: q,k now written to COMPACT qb/kb (lda 1024) instead of interleaved
// qkv (lda 3072) — probes the stride-locality hypothesis (QKV per-tile
// 1.39us @2KB stride vs QK^T 2.02us @6KB stride, same loop/counters).
// kb is passed via the (MODE-0-unused) rsv slot; signature unchanged.
//
// MODE 0: fused QKV epilogue (q->qb, k->kb bf16 + bias; v->vt transposed)
// MODE 2: bf16 P = exp(acc*alpha) + fused row-sum (atomicAdd of bf16-rounded
//         partials into rs[row])
// ---------------------------------------------------------------------------
template <int MODE>
__global__ __launch_bounds__(512, 2)
void gemm256(const unsigned short* __restrict__ A, const unsigned short* __restrict__ B,
             void* __restrict__ Cv,
             const float* __restrict__ b0v, const float* __restrict__ b1v,
             const float* __restrict__ b2v, unsigned short* __restrict__ vt,
             float* __restrict__ rsv,
             int K, int lda, int ldb, int ldc,
             long sA, long sB, long sC, float alpha)
{
    constexpr int AT = 256 * 64;               // elems per A slot (32 KB)
    constexpr int BT = 128 * 64;               // elems per B slot (16 KB)
    __shared__ __align__(16) unsigned short As[3 * AT];   // 96 KB
    __shared__ __align__(16) unsigned short Bs[3 * BT];   // 48 KB

    const int tid  = threadIdx.x;              // 512 threads = 8 waves
    const int wave = tid >> 6;
    const int lane = tid & 63;
    const int l4   = lane & 15;
    const int lh   = lane >> 4;
    const int wm   = wave >> 1;                // 0..3  (M quarter)
    const int wn   = wave & 1;                 // 0..1  (N half)

    const int m0 = blockIdx.x * 256;
    const int n0 = blockIdx.y * 128;
    const int z  = blockIdx.z;
    A += (long)z * sA;
    B += (long)z * sB;

    const int r0 = tid >> 3;                   // 0..63
    const int gc = (tid & 7) ^ (r0 & 7);
    const unsigned short* Ag = A + (long)(m0 + r0) * lda + gc * 8;
    const unsigned short* Bg = B + (long)(n0 + r0) * ldb + gc * 8;
    unsigned short* Al = As + tid * 8;
    unsigned short* Bl = Bs + tid * 8;

    const int NT = K >> 6;                     // K-tiles of 64

    auto stage = [&](int t, int slot, int ph) {
        const long kof = (long)t * 64;
        unsigned short* al = Al + slot * AT;
        unsigned short* bl = Bl + slot * BT;
        if (ph == 0) {
            load_lds_128(Ag + kof,                          al);
            load_lds_128(Ag + kof + (long)64 * lda,         al + 4096);
            load_lds_128(Bg + kof,                          bl);
        } else {
            load_lds_128(Ag + kof + (long)128 * lda,        al + 8192);
            load_lds_128(Ag + kof + (long)192 * lda,        al + 12288);
            load_lds_128(Bg + kof + (long)64 * ldb,         bl + 4096);
        }
    };

    const int aoff = (wm * 64 + l4) * 64;      // + mf*1024 + cs[kk]
    const int boff = (wn * 64 + l4) * 64;      // + nf*1024 + cs[kk]
    const int cs0  = ((0 + lh) ^ (lane & 7)) * 8;
    const int cs1  = ((4 + lh) ^ (lane & 7)) * 8;

    f32x4 acc[4][4] = {};
    bf16x8 a0[4], b0[4], a1[4], b1[4];

    auto ldfrag = [&](bf16x8 (&a)[4], bf16x8 (&b)[4],
                      const unsigned short* Ab, const unsigned short* Bb, int cs) {
#pragma unroll
        for (int mf = 0; mf < 4; ++mf) a[mf] = *(const bf16x8*)(Ab + mf * 1024 + cs);
#pragma unroll
        for (int nf = 0; nf < 4; ++nf) b[nf] = *(const bf16x8*)(Bb + nf * 1024 + cs);
    };
    auto mfma16 = [&](bf16x8 (&a)[4], bf16x8 (&b)[4]) {
        __builtin_amdgcn_s_setprio(1);
#pragma unroll
        for (int mf = 0; mf < 4; ++mf)
#pragma unroll
            for (int nf = 0; nf < 4; ++nf)
                acc[mf][nf] = __builtin_amdgcn_mfma_f32_16x16x32_bf16(
                    a[mf], b[nf], acc[mf][nf], 0, 0, 0);
        __builtin_amdgcn_s_setprio(0);
    };

    // prologue: stage tiles 0,1; drain tile 0 (stage(1) stays in flight)
    stage(0, 0, 0); stage(0, 0, 1);
    stage(1, 1, 0); stage(1, 1, 1);
    asm volatile("s_waitcnt vmcnt(6)" ::: "memory");
    BAR();
    ldfrag(a0, b0, As + aoff, Bs + boff, cs0);   // tile 0, kk=0

    int sl = 0;
    for (int t = 0; t < NT; ++t) {
        const unsigned short* Ab = As + sl * AT + aoff;
        const unsigned short* Bb = Bs + sl * BT + boff;
        const int st  = (sl >= 1) ? sl - 1 : 2;        // (sl+2)%3
        const int nsl = (sl == 2) ? 0 : sl + 1;

        // phase A: issue rd(t,kk1), stage, MFMA on (t,kk0)
        ldfrag(a1, b1, Ab, Bb, cs1);
        if (t + 2 < NT) stage(t + 2, st, 0);
        mfma16(a0, b0);                 // counted lgkmcnt: a1/b1 in flight

        // phase B: stage, drain+barrier, rd(t+1,kk0), MFMA (t,kk1)
        if (t + 2 < NT) stage(t + 2, st, 1);
        asm volatile("s_waitcnt lgkmcnt(0)" ::: "memory");   // WAR invariant
        if (t < NT - 2) asm volatile("s_waitcnt vmcnt(6)" ::: "memory");
        else            asm volatile("s_waitcnt vmcnt(0)" ::: "memory");
        BAR();
        if (t + 1 < NT)
            ldfrag(a0, b0, As + nsl * AT + aoff, Bs + nsl * BT + boff, cs0);
        mfma16(a1, b1);
        sl = nsl;
    }

    // ---- epilogue ----
    // C/D 16x16x32: col = lane&15 (+nf*16), row = (lane>>4)*4 + reg (+mf*16)
    const int r0c = m0 + wm * 64 + lh * 4;
    const int c0c = n0 + wn * 64 + l4;

    if (MODE == 0) {
        if (n0 >= 2048) {
            // V columns -> vt[b][d][m] (+bias), packed 4-m ushort4 stores
#pragma unroll
            for (int nf = 0; nf < 4; ++nf) {
                const int d = c0c + nf * 16 - 2048;
                const float bias = b2v[d];
#pragma unroll
                for (int mf = 0; mf < 4; ++mf) {
                    const int row = r0c + mf * 16;
                    const int bb = row >> 11;
                    const int mm = row & 2047;
                    ushort4 u;
                    u.x = f2bf(acc[mf][nf][0] + bias);
                    u.y = f2bf(acc[mf][nf][1] + bias);
                    u.z = f2bf(acc[mf][nf][2] + bias);
                    u.w = f2bf(acc[mf][nf][3] + bias);
                    *(ushort4*)(vt + ((long)bb * DIM + d) * SEQ + mm) = u;
                }
            }
        } else {
            // q block (n0<1024) -> qb, k block -> kb; both lda 1024 compact
            const bool isq = (n0 < 1024);
            unsigned short* dst = isq ? (unsigned short*)Cv
                                      : (unsigned short*)rsv;   // kb via rsv slot
            const float* bp = isq ? b0v : b1v;
            const int coff = isq ? 0 : 1024;
#pragma unroll
            for (int nf = 0; nf < 4; ++nf) {
                const int col = c0c + nf * 16 - coff;
                const float bias = bp[col];
#pragma unroll
                for (int mf = 0; mf < 4; ++mf)
#pragma unroll
                    for (int r = 0; r < 4; ++r)
                        dst[(long)(r0c + mf * 16 + r) * ldc + col] =
                            f2bf(acc[mf][nf][r] + bias);
            }
        }
    } else {  // MODE 2: P = exp(acc*alpha) bf16 + fused row-sum atomics
        unsigned short* C16 = (unsigned short*)Cv + (long)z * sC;
        float* rs = rsv + (long)z * SEQ;
#pragma unroll
        for (int mf = 0; mf < 4; ++mf)
#pragma unroll
            for (int r = 0; r < 4; ++r) {
                const int rowi = r0c + mf * 16 + r;
                float s = 0.f;
#pragma unroll
                for (int nf = 0; nf < 4; ++nf) {
                    const int col = c0c + nf * 16;
                    const unsigned short pu = f2bf(__expf(acc[mf][nf][r] * alpha));
                    C16[(long)rowi * ldc + col] = pu;
                    s += bfu2f(pu);            // sum the ROUNDED value
                }
                // reduce over the 16-lane l4 group (same lh -> same rows)
                s += __shfl_xor(s, 1);
                s += __shfl_xor(s, 2);
                s += __shfl_xor(s, 4);
                s += __shfl_xor(s, 8);
                if (l4 == 0) atomicAdd(rs + rowi, s);
            }
    }
}

// ---------------------------------------------------------------------------
// Standalone PV kernel (rule #19: NOT a gemm256 instantiation).
// C = (P . vt^T) / rs[row], fp32.  K-loop identical to gemm256.
// ---------------------------------------------------------------------------
__global__ __launch_bounds__(512, 2)
void gemm_pv(const unsigned short* __restrict__ A, const unsigned short* __restrict__ B,
             float* __restrict__ C, const float* __restrict__ rsv,
             int K, int lda, int ldb, int ldc,
             long sA, long sB, long sC)
{
    constexpr int AT = 256 * 64;
    constexpr int BT = 128 * 64;
    __shared__ __align__(16) unsigned short As[3 * AT];   // 96 KB
    __shared__ __align__(16) unsigned short Bs[3 * BT];   // 48 KB

    const int tid  = threadIdx.x;
    const int wave = tid >> 6;
    const int lane = tid & 63;
    const int l4   = lane & 15;
    const int lh   = lane >> 4;
    const int wm   = wave >> 1;
    const int wn   = wave & 1;

    const int m0 = blockIdx.x * 256;
    const int n0 = blockIdx.y * 128;
    const int z  = blockIdx.z;
    A += (long)z * sA;
    B += (long)z * sB;

    const int r0 = tid >> 3;
    const int gc = (tid & 7) ^ (r0 & 7);
    const unsigned short* Ag = A + (long)(m0 + r0) * lda + gc * 8;
    const unsigned short* Bg = B + (long)(n0 + r0) * ldb + gc * 8;
    unsigned short* Al = As + tid * 8;
    unsigned short* Bl = Bs + tid * 8;

    const int NT = K >> 6;

    auto stage = [&](int t, int slot, int ph) {
        const long kof = (long)t * 64;
        unsigned short* al = Al + slot * AT;
        unsigned short* bl = Bl + slot * BT;
        if (ph == 0) {
            load_lds_128(Ag + kof,                          al);
            load_lds_128(Ag + kof + (long)64 * lda,         al + 4096);
            load_lds_128(Bg + kof,                          bl);
        } else {
            load_lds_128(Ag + kof + (long)128 * lda,        al + 8192);
            load_lds_128(Ag + kof + (long)192 * lda,        al + 12288);
            load_lds_128(Bg + kof + (long)64 * ldb,         bl + 4096);
        }
    };

    const int aoff = (wm * 64 + l4) * 64;
    const int boff = (wn * 64 + l4) * 64;
    const int cs0  = ((0 + lh) ^ (lane & 7)) * 8;
    const int cs1  = ((4 + lh) ^ (lane & 7)) * 8;

    f32x4 acc[4][4] = {};
    bf16x8 a0[4], b0[4], a1[4], b1[4];

    auto ldfrag = [&](bf16x8 (&a)[4], bf16x8 (&b)[4],
                      const unsigned short* Ab, const unsigned short* Bb, int cs) {
#pragma unroll
        for (int mf = 0; mf < 4; ++mf) a[mf] = *(const bf16x8*)(Ab + mf * 1024 + cs);
#pragma unroll
        for (int nf = 0; nf < 4; ++nf) b[nf] = *(const bf16x8*)(Bb + nf * 1024 + cs);
    };
    auto mfma16 = [&](bf16x8 (&a)[4], bf16x8 (&b)[4]) {
        __builtin_amdgcn_s_setprio(1);
#pragma unroll
        for (int mf = 0; mf < 4; ++mf)
#pragma unroll
            for (int nf = 0; nf < 4; ++nf)
                acc[mf][nf] = __builtin_amdgcn_mfma_f32_16x16x32_bf16(
                    a[mf], b[nf], acc[mf][nf], 0, 0, 0);
        __builtin_amdgcn_s_setprio(0);
    };

    stage(0, 0, 0); stage(0, 0, 1);
    stage(1, 1, 0); stage(1, 1, 1);
    asm volatile("s_waitcnt vmcnt(6)" ::: "memory");
    BAR();
    ldfrag(a0, b0, As + aoff, Bs + boff, cs0);

    int sl = 0;
    for (int t = 0; t < NT; ++t) {
        const unsigned short* Ab = As + sl * AT + aoff;
        const unsigned short* Bb = Bs + sl * BT + boff;
        const int st  = (sl >= 1) ? sl - 1 : 2;
        const int nsl = (sl == 2) ? 0 : sl + 1;

        ldfrag(a1, b1, Ab, Bb, cs1);
        if (t + 2 < NT) stage(t + 2, st, 0);
        mfma16(a0, b0);

        if (t + 2 < NT) stage(t + 2, st, 1);
        asm volatile("s_waitcnt lgkmcnt(0)" ::: "memory");
        if (t < NT - 2) asm volatile("s_waitcnt vmcnt(6)" ::: "memory");
        else            asm volatile("s_waitcnt vmcnt(0)" ::: "memory");
        BAR();
        if (t + 1 < NT)
            ldfrag(a0, b0, As + nsl * AT + aoff, Bs + nsl * BT + boff, cs0);
        mfma16(a1, b1);
        sl = nsl;
    }

    // epilogue: C = acc / rs[row]
    float* Cz = C + (long)z * sC;
    const float* rsp = rsv + (long)z * SEQ;
    const int r0c = m0 + wm * 64 + lh * 4;
    const int c0c = n0 + wn * 64 + l4;
#pragma unroll
    for (int mf = 0; mf < 4; ++mf) {
        const int rowb = r0c + mf * 16;
        const float4 rs4 = *(const float4*)(rsp + rowb);
        const float i0 = 1.0f / rs4.x, i1 = 1.0f / rs4.y;
        const float i2 = 1.0f / rs4.z, i3 = 1.0f / rs4.w;
#pragma unroll
        for (int nf = 0; nf < 4; ++nf) {
            const int col = c0c + nf * 16;
            Cz[(long)(rowb + 0) * ldc + col] = acc[mf][nf][0] * i0;
            Cz[(long)(rowb + 1) * ldc + col] = acc[mf][nf][1] * i1;
            Cz[(long)(rowb + 2) * ldc + col] = acc[mf][nf][2] * i2;
            Cz[(long)(rowb + 3) * ldc + col] = acc[mf][nf][3] * i3;
        }
    }
}

// ---------------------------------------------------------------------------
// Merged preprocessing (1 dispatch): x->bf16, W{q,k,v}->bf16, rs zero.
// ---------------------------------------------------------------------------
#define PREP_BLOCKS (8192 + 3072 + 32)

__global__ __launch_bounds__(256)
void prep(const float* __restrict__ x,
          const float* __restrict__ Wq, const float* __restrict__ Wk,
          const float* __restrict__ Wv,
          unsigned short* __restrict__ xb, unsigned short* __restrict__ Wb,
          float* __restrict__ rs)
{
    const int b = blockIdx.x;
    if (b < 8192) {
        const int i = b * 256 + threadIdx.x;
        float4 f = ((const float4*)x)[i];
        ushort4 u;
        u.x = f2bf(f.x); u.y = f2bf(f.y); u.z = f2bf(f.z); u.w = f2bf(f.w);
        ((ushort4*)xb)[i] = u;
    } else if (b < 8192 + 3072) {
        const int idx = (b - 8192) * 256 + threadIdx.x;   // 0 .. 786431
        const int sel = idx / (DIM * DIM / 4);
        const int j   = idx - sel * (DIM * DIM / 4);
        const float* src = (sel == 0) ? Wq : ((sel == 1) ? Wk : Wv);
        float4 f = ((const float4*)src)[j];
        ushort4 u;
        u.x = f2bf(f.x); u.y = f2bf(f.y); u.z = f2bf(f.z); u.w = f2bf(f.w);
        ((ushort4*)(Wb + (long)sel * DIM * DIM))[j] = u;
    } else {
        const int idx = (b - 8192 - 3072) * 256 + threadIdx.x;
        if (idx < NTOK) rs[idx] = 0.f;
    }
}

// ---------------------------------------------------------------------------
extern "C" void kernel_launch(void* const* d_in, const int* in_sizes, int n_in,
                              void* d_out, int out_size, void* d_ws, size_t ws_size,
                              hipStream_t stream)
{
    const float* x  = (const float*)d_in[0];
    const float* Wq = (const float*)d_in[1];
    const float* bq = (const float*)d_in[2];
    const float* Wk = (const float*)d_in[3];
    const float* bk = (const float*)d_in[4];
    const float* Wv = (const float*)d_in[5];
    const float* bv = (const float*)d_in[6];
    float* out = (float*)d_out;

    // Workspace layout — COMPACTED r11 (102MB+32KB span, was 160MB+32KB):
    //  [0,16MB):    xb bf16 [8192][1024]
    //  [16,22MB):   Wb bf16 [3][1024][1024]
    //  [22,38MB):   qb bf16 [8192][1024]   (compact q, lda 1024)
    //  [38,54MB):   kb bf16 [8192][1024]   (compact k, lda 1024)
    //  [54,70MB):   vt bf16 [4][1024][2048]
    //  [70,102MB):  P  bf16 [4][2048][2048] (unnormalized exp)
    //  [102MB,+32KB): rs fp32 [8192]
    char* ws = (char*)d_ws;
    unsigned short* xb = (unsigned short*)ws;
    unsigned short* Wb = (unsigned short*)(ws + 16u * 1024 * 1024);
    unsigned short* qb = (unsigned short*)(ws + 22u * 1024 * 1024);
    unsigned short* kb = (unsigned short*)(ws + 38u * 1024 * 1024);
    unsigned short* vt = (unsigned short*)(ws + 54u * 1024 * 1024);
    unsigned short* P  = (unsigned short*)(ws + 70u * 1024 * 1024);
    float*          rs = (float*)(ws + 102u * 1024 * 1024);

    const float scale = 0.03125f;   // 1/sqrt(1024)
    dim3 blk512(512);

    // 1) merged converts + rs zero (one dispatch)
    prep<<<PREP_BLOCKS, 256, 0, stream>>>(x, Wq, Wk, Wv, xb, Wb, rs);

    // 2) fused QKV projection, 256x128 tiles -> 32*24 = 768 blocks.
    //    q -> qb (Cv), k -> kb (via rsv slot), v -> vt.  ldc = 1024.
    gemm256<0><<<dim3(NTOK / 256, NQKV / 128), blk512, 0, stream>>>(
        xb, Wb, qb, bq, bk, bv, vt, (float*)kb,
        DIM, DIM, DIM, DIM, 0, 0, 0, 1.0f);

    // 3) P = exp(q.k^T * scale) + fused row-sum; A=qb, B=kb (2KB strides).
    //    8*16*4 = 512 blocks
    gemm256<2><<<dim3(SEQ / 256, SEQ / 128, 4), blk512, 0, stream>>>(
        qb, kb, P, nullptr, nullptr, nullptr, nullptr, rs,
        DIM, DIM, DIM, SEQ,
        (long)SEQ * DIM, (long)SEQ * DIM, (long)SEQ * SEQ, scale);

    // 4) out = (P.vt^T) / rs, 256x128 tiles -> 8*8*4 = 256 blocks
    gemm_pv<<<dim3(SEQ / 256, DIM / 128, 4), blk512, 0, stream>>>(
        P, vt, out, rs,
        SEQ, SEQ, SEQ, DIM,
        (long)SEQ * SEQ, (long)DIM * SEQ, (long)SEQ * DIM);
}

// Round 12
// 236.841 us; speedup vs baseline: 1.0293x; 1.0161x over previous
//
#include <hip/hip_runtime.h>

#define SEQ  2048
#define DIM  1024
#define NTOK 8192   // 4*SEQ
#define NQKV 3072

typedef __attribute__((ext_vector_type(8))) __bf16 bf16x8;
typedef __attribute__((ext_vector_type(4))) float  f32x4;

__device__ __forceinline__ unsigned short f2bf(float f) {
    unsigned int u = __float_as_uint(f);
    u += 0x7fffu + ((u >> 16) & 1u);          // round-to-nearest-even
    return (unsigned short)(u >> 16);
}

__device__ __forceinline__ float bfu2f(unsigned int lo16) {
    return __uint_as_float(lo16 << 16);
}

__device__ __forceinline__ void load_lds_128(const unsigned short* g, unsigned short* l) {
    __builtin_amdgcn_global_load_lds(
        (const __attribute__((address_space(1))) void*)g,
        (__attribute__((address_space(3))) void*)l, 16, 0, 0);
}

#define BAR() asm volatile("s_barrier" ::: "memory")

// ---------------------------------------------------------------------------
// r3-form K-loop (best measured: 64.0-66.7 us, r10/r11).  NT GEMM, bf16 MFMA
// 16x16x32, 256x128 block, BK=64, 8 waves 4M x 2N (64x64/wave, acc[4][4]).
// 3-slot LDS ring, distance-2 prefetch, counted vmcnt(6), ONE barrier per
// K-tile, register fragment double-buffer (counted lgkmcnt overlap).
//
// LDS rows 128B; slot c of row r holds global chunk g = c ^ (r&7) ->
// ds_read_b128 2-way (free); SQ_LDS_BANK_CONFLICT==0 verified r2-r11.
//
// rule-#19 (r9/r10 measured): this template compiles with EXACTLY MODE 0
// and MODE 2; a third instantiation cost +14% on ALL modes.  PV is the
// standalone gemm_pv.  K-loop below is byte-identical to r11.
//
// r12: 2-D rectangular XCD remap for MODE 2 (and gemm_pv).  Mechanism:
// default XCD = lin%8 = bx gives each XCD one A-panel (high reuse) but
// streams the ENTIRE B operand with zero in-XCD reuse (~8-16MB/window,
// 8x redundant across XCDs from L3).  Remapping each XCD's co-resident
// set to a (4bx x 8by) rectangle gives A 8x and B 4x in-L2 reuse,
// cutting per-XCD pulled bytes 9->4MB (QK) / 20->8MB (PV).  Unlike r8's
// failed 1-D chunking (which spanned all bx -> 4x FETCH), this keeps both
// coordinates local.  GUARD: FETCH_SIZE must stay ~49MB, else revert.
// QKV (MODE 0) keeps identity mapping (weights are L2-hot already).
//
// MODE 0: fused QKV epilogue (q->qb, k->kb bf16 + bias; v->vt transposed)
// MODE 2: bf16 P = exp(acc*alpha) + fused row-sum (atomicAdd of bf16-rounded
//         partials into rs[row])
// ---------------------------------------------------------------------------
template <int MODE>
__global__ __launch_bounds__(512, 2)
void gemm256(const unsigned short* __restrict__ A, const unsigned short* __restrict__ B,
             void* __restrict__ Cv,
             const float* __restrict__ b0v, const float* __restrict__ b1v,
             const float* __restrict__ b2v, unsigned short* __restrict__ vt,
             float* __restrict__ rsv,
             int K, int lda, int ldb, int ldc,
             long sA, long sB, long sC, float alpha)
{
    constexpr int AT = 256 * 64;               // elems per A slot (32 KB)
    constexpr int BT = 128 * 64;               // elems per B slot (16 KB)
    __shared__ __align__(16) unsigned short As[3 * AT];   // 96 KB
    __shared__ __align__(16) unsigned short Bs[3 * BT];   // 48 KB

    const int tid  = threadIdx.x;              // 512 threads = 8 waves
    const int wave = tid >> 6;
    const int lane = tid & 63;
    const int l4   = lane & 15;
    const int lh   = lane >> 4;
    const int wm   = wave >> 1;                // 0..3  (M quarter)
    const int wn   = wave & 1;                 // 0..1  (N half)

    int bx, by, z;
    if constexpr (MODE == 2) {
        // grid (8,16,4): lin = x + 8y + 128z.  XCD t = lin&7 gets rectangle
        // (bx = (t&1)*4 + w&3, by = w>>2, z = t>>1) -- bijective.
        const int lin = blockIdx.x + (blockIdx.y << 3) + (blockIdx.z << 7);
        const int t = lin & 7, w = lin >> 3;
        bx = (t & 1) * 4 + (w & 3);
        z  = t >> 1;
        by = w >> 2;
    } else {
        bx = blockIdx.x; by = blockIdx.y; z = blockIdx.z;
    }
    const int m0 = bx * 256;
    const int n0 = by * 128;
    A += (long)z * sA;
    B += (long)z * sB;

    const int r0 = tid >> 3;                   // 0..63
    const int gc = (tid & 7) ^ (r0 & 7);
    const unsigned short* Ag = A + (long)(m0 + r0) * lda + gc * 8;
    const unsigned short* Bg = B + (long)(n0 + r0) * ldb + gc * 8;
    unsigned short* Al = As + tid * 8;
    unsigned short* Bl = Bs + tid * 8;

    const int NT = K >> 6;                     // K-tiles of 64

    auto stage = [&](int t, int slot, int ph) {
        const long kof = (long)t * 64;
        unsigned short* al = Al + slot * AT;
        unsigned short* bl = Bl + slot * BT;
        if (ph == 0) {
            load_lds_128(Ag + kof,                          al);
            load_lds_128(Ag + kof + (long)64 * lda,         al + 4096);
            load_lds_128(Bg + kof,                          bl);
        } else {
            load_lds_128(Ag + kof + (long)128 * lda,        al + 8192);
            load_lds_128(Ag + kof + (long)192 * lda,        al + 12288);
            load_lds_128(Bg + kof + (long)64 * ldb,         bl + 4096);
        }
    };

    const int aoff = (wm * 64 + l4) * 64;      // + mf*1024 + cs[kk]
    const int boff = (wn * 64 + l4) * 64;      // + nf*1024 + cs[kk]
    const int cs0  = ((0 + lh) ^ (lane & 7)) * 8;
    const int cs1  = ((4 + lh) ^ (lane & 7)) * 8;

    f32x4 acc[4][4] = {};
    bf16x8 a0[4], b0[4], a1[4], b1[4];

    auto ldfrag = [&](bf16x8 (&a)[4], bf16x8 (&b)[4],
                      const unsigned short* Ab, const unsigned short* Bb, int cs) {
#pragma unroll
        for (int mf = 0; mf < 4; ++mf) a[mf] = *(const bf16x8*)(Ab + mf * 1024 + cs);
#pragma unroll
        for (int nf = 0; nf < 4; ++nf) b[nf] = *(const bf16x8*)(Bb + nf * 1024 + cs);
    };
    auto mfma16 = [&](bf16x8 (&a)[4], bf16x8 (&b)[4]) {
        __builtin_amdgcn_s_setprio(1);
#pragma unroll
        for (int mf = 0; mf < 4; ++mf)
#pragma unroll
            for (int nf = 0; nf < 4; ++nf)
                acc[mf][nf] = __builtin_amdgcn_mfma_f32_16x16x32_bf16(
                    a[mf], b[nf], acc[mf][nf], 0, 0, 0);
        __builtin_amdgcn_s_setprio(0);
    };

    // prologue: stage tiles 0,1; drain tile 0 (stage(1) stays in flight)
    stage(0, 0, 0); stage(0, 0, 1);
    stage(1, 1, 0); stage(1, 1, 1);
    asm volatile("s_waitcnt vmcnt(6)" ::: "memory");
    BAR();
    ldfrag(a0, b0, As + aoff, Bs + boff, cs0);   // tile 0, kk=0

    int sl = 0;
    for (int t = 0; t < NT; ++t) {
        const unsigned short* Ab = As + sl * AT + aoff;
        const unsigned short* Bb = Bs + sl * BT + boff;
        const int st  = (sl >= 1) ? sl - 1 : 2;        // (sl+2)%3
        const int nsl = (sl == 2) ? 0 : sl + 1;

        // phase A: issue rd(t,kk1), stage, MFMA on (t,kk0)
        ldfrag(a1, b1, Ab, Bb, cs1);
        if (t + 2 < NT) stage(t + 2, st, 0);
        mfma16(a0, b0);                 // counted lgkmcnt: a1/b1 in flight

        // phase B: stage, drain+barrier, rd(t+1,kk0), MFMA (t,kk1)
        if (t + 2 < NT) stage(t + 2, st, 1);
        asm volatile("s_waitcnt lgkmcnt(0)" ::: "memory");   // WAR invariant
        if (t < NT - 2) asm volatile("s_waitcnt vmcnt(6)" ::: "memory");
        else            asm volatile("s_waitcnt vmcnt(0)" ::: "memory");
        BAR();
        if (t + 1 < NT)
            ldfrag(a0, b0, As + nsl * AT + aoff, Bs + nsl * BT + boff, cs0);
        mfma16(a1, b1);
        sl = nsl;
    }

    // ---- epilogue ----
    // C/D 16x16x32: col = lane&15 (+nf*16), row = (lane>>4)*4 + reg (+mf*16)
    const int r0c = m0 + wm * 64 + lh * 4;
    const int c0c = n0 + wn * 64 + l4;

    if (MODE == 0) {
        if (n0 >= 2048) {
            // V columns -> vt[b][d][m] (+bias), packed 4-m ushort4 stores
#pragma unroll
            for (int nf = 0; nf < 4; ++nf) {
                const int d = c0c + nf * 16 - 2048;
                const float bias = b2v[d];
#pragma unroll
                for (int mf = 0; mf < 4; ++mf) {
                    const int row = r0c + mf * 16;
                    const int bb = row >> 11;
                    const int mm = row & 2047;
                    ushort4 u;
                    u.x = f2bf(acc[mf][nf][0] + bias);
                    u.y = f2bf(acc[mf][nf][1] + bias);
                    u.z = f2bf(acc[mf][nf][2] + bias);
                    u.w = f2bf(acc[mf][nf][3] + bias);
                    *(ushort4*)(vt + ((long)bb * DIM + d) * SEQ + mm) = u;
                }
            }
        } else {
            // q block (n0<1024) -> qb, k block -> kb; both lda 1024 compact
            const bool isq = (n0 < 1024);
            unsigned short* dst = isq ? (unsigned short*)Cv
                                      : (unsigned short*)rsv;   // kb via rsv slot
            const float* bp = isq ? b0v : b1v;
            const int coff = isq ? 0 : 1024;
#pragma unroll
            for (int nf = 0; nf < 4; ++nf) {
                const int col = c0c + nf * 16 - coff;
                const float bias = bp[col];
#pragma unroll
                for (int mf = 0; mf < 4; ++mf)
#pragma unroll
                    for (int r = 0; r < 4; ++r)
                        dst[(long)(r0c + mf * 16 + r) * ldc + col] =
                            f2bf(acc[mf][nf][r] + bias);
            }
        }
    } else {  // MODE 2: P = exp(acc*alpha) bf16 + fused row-sum atomics
        unsigned short* C16 = (unsigned short*)Cv + (long)z * sC;
        float* rs = rsv + (long)z * SEQ;
#pragma unroll
        for (int mf = 0; mf < 4; ++mf)
#pragma unroll
            for (int r = 0; r < 4; ++r) {
                const int rowi = r0c + mf * 16 + r;
                float s = 0.f;
#pragma unroll
                for (int nf = 0; nf < 4; ++nf) {
                    const int col = c0c + nf * 16;
                    const unsigned short pu = f2bf(__expf(acc[mf][nf][r] * alpha));
                    C16[(long)rowi * ldc + col] = pu;
                    s += bfu2f(pu);            // sum the ROUNDED value
                }
                // reduce over the 16-lane l4 group (same lh -> same rows)
                s += __shfl_xor(s, 1);
                s += __shfl_xor(s, 2);
                s += __shfl_xor(s, 4);
                s += __shfl_xor(s, 8);
                if (l4 == 0) atomicAdd(rs + rowi, s);
            }
    }
}

// ---------------------------------------------------------------------------
// Standalone PV kernel (rule #19: NOT a gemm256 instantiation).
// C = (P . vt^T) / rs[row], fp32.  K-loop identical to gemm256.
// r12: same 2-D rectangular XCD remap (grid (8,8,4)).
// ---------------------------------------------------------------------------
__global__ __launch_bounds__(512, 2)
void gemm_pv(const unsigned short* __restrict__ A, const unsigned short* __restrict__ B,
             float* __restrict__ C, const float* __restrict__ rsv,
             int K, int lda, int ldb, int ldc,
             long sA, long sB, long sC)
{
    constexpr int AT = 256 * 64;
    constexpr int BT = 128 * 64;
    __shared__ __align__(16) unsigned short As[3 * AT];   // 96 KB
    __shared__ __align__(16) unsigned short Bs[3 * BT];   // 48 KB

    const int tid  = threadIdx.x;
    const int wave = tid >> 6;
    const int lane = tid & 63;
    const int l4   = lane & 15;
    const int lh   = lane >> 4;
    const int wm   = wave >> 1;
    const int wn   = wave & 1;

    // grid (8,8,4): lin = x + 8y + 64z.  Rectangle remap (r12, see gemm256).
    const int lin = blockIdx.x + (blockIdx.y << 3) + (blockIdx.z << 6);
    const int tx = lin & 7, w = lin >> 3;
    const int bx = (tx & 1) * 4 + (w & 3);
    const int z  = tx >> 1;
    const int by = w >> 2;

    const int m0 = bx * 256;
    const int n0 = by * 128;
    A += (long)z * sA;
    B += (long)z * sB;

    const int r0 = tid >> 3;
    const int gc = (tid & 7) ^ (r0 & 7);
    const unsigned short* Ag = A + (long)(m0 + r0) * lda + gc * 8;
    const unsigned short* Bg = B + (long)(n0 + r0) * ldb + gc * 8;
    unsigned short* Al = As + tid * 8;
    unsigned short* Bl = Bs + tid * 8;

    const int NT = K >> 6;

    auto stage = [&](int t, int slot, int ph) {
        const long kof = (long)t * 64;
        unsigned short* al = Al + slot * AT;
        unsigned short* bl = Bl + slot * BT;
        if (ph == 0) {
            load_lds_128(Ag + kof,                          al);
            load_lds_128(Ag + kof + (long)64 * lda,         al + 4096);
            load_lds_128(Bg + kof,                          bl);
        } else {
            load_lds_128(Ag + kof + (long)128 * lda,        al + 8192);
            load_lds_128(Ag + kof + (long)192 * lda,        al + 12288);
            load_lds_128(Bg + kof + (long)64 * ldb,         bl + 4096);
        }
    };

    const int aoff = (wm * 64 + l4) * 64;
    const int boff = (wn * 64 + l4) * 64;
    const int cs0  = ((0 + lh) ^ (lane & 7)) * 8;
    const int cs1  = ((4 + lh) ^ (lane & 7)) * 8;

    f32x4 acc[4][4] = {};
    bf16x8 a0[4], b0[4], a1[4], b1[4];

    auto ldfrag = [&](bf16x8 (&a)[4], bf16x8 (&b)[4],
                      const unsigned short* Ab, const unsigned short* Bb, int cs) {
#pragma unroll
        for (int mf = 0; mf < 4; ++mf) a[mf] = *(const bf16x8*)(Ab + mf * 1024 + cs);
#pragma unroll
        for (int nf = 0; nf < 4; ++nf) b[nf] = *(const bf16x8*)(Bb + nf * 1024 + cs);
    };
    auto mfma16 = [&](bf16x8 (&a)[4], bf16x8 (&b)[4]) {
        __builtin_amdgcn_s_setprio(1);
#pragma unroll
        for (int mf = 0; mf < 4; ++mf)
#pragma unroll
            for (int nf = 0; nf < 4; ++nf)
                acc[mf][nf] = __builtin_amdgcn_mfma_f32_16x16x32_bf16(
                    a[mf], b[nf], acc[mf][nf], 0, 0, 0);
        __builtin_amdgcn_s_setprio(0);
    };

    stage(0, 0, 0); stage(0, 0, 1);
    stage(1, 1, 0); stage(1, 1, 1);
    asm volatile("s_waitcnt vmcnt(6)" ::: "memory");
    BAR();
    ldfrag(a0, b0, As + aoff, Bs + boff, cs0);

    int sl = 0;
    for (int t = 0; t < NT; ++t) {
        const unsigned short* Ab = As + sl * AT + aoff;
        const unsigned short* Bb = Bs + sl * BT + boff;
        const int st  = (sl >= 1) ? sl - 1 : 2;
        const int nsl = (sl == 2) ? 0 : sl + 1;

        ldfrag(a1, b1, Ab, Bb, cs1);
        if (t + 2 < NT) stage(t + 2, st, 0);
        mfma16(a0, b0);

        if (t + 2 < NT) stage(t + 2, st, 1);
        asm volatile("s_waitcnt lgkmcnt(0)" ::: "memory");
        if (t < NT - 2) asm volatile("s_waitcnt vmcnt(6)" ::: "memory");
        else            asm volatile("s_waitcnt vmcnt(0)" ::: "memory");
        BAR();
        if (t + 1 < NT)
            ldfrag(a0, b0, As + nsl * AT + aoff, Bs + nsl * BT + boff, cs0);
        mfma16(a1, b1);
        sl = nsl;
    }

    // epilogue: C = acc / rs[row]
    float* Cz = C + (long)z * sC;
    const float* rsp = rsv + (long)z * SEQ;
    const int r0c = m0 + wm * 64 + lh * 4;
    const int c0c = n0 + wn * 64 + l4;
#pragma unroll
    for (int mf = 0; mf < 4; ++mf) {
        const int rowb = r0c + mf * 16;
        const float4 rs4 = *(const float4*)(rsp + rowb);
        const float i0 = 1.0f / rs4.x, i1 = 1.0f / rs4.y;
        const float i2 = 1.0f / rs4.z, i3 = 1.0f / rs4.w;
#pragma unroll
        for (int nf = 0; nf < 4; ++nf) {
            const int col = c0c + nf * 16;
            Cz[(long)(rowb + 0) * ldc + col] = acc[mf][nf][0] * i0;
            Cz[(long)(rowb + 1) * ldc + col] = acc[mf][nf][1] * i1;
            Cz[(long)(rowb + 2) * ldc + col] = acc[mf][nf][2] * i2;
            Cz[(long)(rowb + 3) * ldc + col] = acc[mf][nf][3] * i3;
        }
    }
}

// ---------------------------------------------------------------------------
// Merged preprocessing (1 dispatch): x->bf16, W{q,k,v}->bf16, rs zero.
// ---------------------------------------------------------------------------
#define PREP_BLOCKS (8192 + 3072 + 32)

__global__ __launch_bounds__(256)
void prep(const float* __restrict__ x,
          const float* __restrict__ Wq, const float* __restrict__ Wk,
          const float* __restrict__ Wv,
          unsigned short* __restrict__ xb, unsigned short* __restrict__ Wb,
          float* __restrict__ rs)
{
    const int b = blockIdx.x;
    if (b < 8192) {
        const int i = b * 256 + threadIdx.x;
        float4 f = ((const float4*)x)[i];
        ushort4 u;
        u.x = f2bf(f.x); u.y = f2bf(f.y); u.z = f2bf(f.z); u.w = f2bf(f.w);
        ((ushort4*)xb)[i] = u;
    } else if (b < 8192 + 3072) {
        const int idx = (b - 8192) * 256 + threadIdx.x;   // 0 .. 786431
        const int sel = idx / (DIM * DIM / 4);
        const int j   = idx - sel * (DIM * DIM / 4);
        const float* src = (sel == 0) ? Wq : ((sel == 1) ? Wk : Wv);
        float4 f = ((const float4*)src)[j];
        ushort4 u;
        u.x = f2bf(f.x); u.y = f2bf(f.y); u.z = f2bf(f.z); u.w = f2bf(f.w);
        ((ushort4*)(Wb + (long)sel * DIM * DIM))[j] = u;
    } else {
        const int idx = (b - 8192 - 3072) * 256 + threadIdx.x;
        if (idx < NTOK) rs[idx] = 0.f;
    }
}

// ---------------------------------------------------------------------------
extern "C" void kernel_launch(void* const* d_in, const int* in_sizes, int n_in,
                              void* d_out, int out_size, void* d_ws, size_t ws_size,
                              hipStream_t stream)
{
    const float* x  = (const float*)d_in[0];
    const float* Wq = (const float*)d_in[1];
    const float* bq = (const float*)d_in[2];
    const float* Wk = (const float*)d_in[3];
    const float* bk = (const float*)d_in[4];
    const float* Wv = (const float*)d_in[5];
    const float* bv = (const float*)d_in[6];
    float* out = (float*)d_out;

    // Workspace layout (102MB+32KB span):
    //  [0,16MB):    xb bf16 [8192][1024]
    //  [16,22MB):   Wb bf16 [3][1024][1024]
    //  [22,38MB):   qb bf16 [8192][1024]   (compact q, lda 1024)
    //  [38,54MB):   kb bf16 [8192][1024]   (compact k, lda 1024)
    //  [54,70MB):   vt bf16 [4][1024][2048]
    //  [70,102MB):  P  bf16 [4][2048][2048] (unnormalized exp)
    //  [102MB,+32KB): rs fp32 [8192]
    char* ws = (char*)d_ws;
    unsigned short* xb = (unsigned short*)ws;
    unsigned short* Wb = (unsigned short*)(ws + 16u * 1024 * 1024);
    unsigned short* qb = (unsigned short*)(ws + 22u * 1024 * 1024);
    unsigned short* kb = (unsigned short*)(ws + 38u * 1024 * 1024);
    unsigned short* vt = (unsigned short*)(ws + 54u * 1024 * 1024);
    unsigned short* P  = (unsigned short*)(ws + 70u * 1024 * 1024);
    float*          rs = (float*)(ws + 102u * 1024 * 1024);

    const float scale = 0.03125f;   // 1/sqrt(1024)
    dim3 blk512(512);

    // 1) merged converts + rs zero (one dispatch)
    prep<<<PREP_BLOCKS, 256, 0, stream>>>(x, Wq, Wk, Wv, xb, Wb, rs);

    // 2) fused QKV projection, 256x128 tiles -> 32*24 = 768 blocks.
    gemm256<0><<<dim3(NTOK / 256, NQKV / 128), blk512, 0, stream>>>(
        xb, Wb, qb, bq, bk, bv, vt, (float*)kb,
        DIM, DIM, DIM, DIM, 0, 0, 0, 1.0f);

    // 3) P = exp(q.k^T * scale) + fused row-sum; XCD-rect remap inside.
    //    8*16*4 = 512 blocks
    gemm256<2><<<dim3(SEQ / 256, SEQ / 128, 4), blk512, 0, stream>>>(
        qb, kb, P, nullptr, nullptr, nullptr, nullptr, rs,
        DIM, DIM, DIM, SEQ,
        (long)SEQ * DIM, (long)SEQ * DIM, (long)SEQ * SEQ, scale);

    // 4) out = (P.vt^T) / rs; XCD-rect remap inside.  8*8*4 = 256 blocks
    gemm_pv<<<dim3(SEQ / 256, DIM / 128, 4), blk512, 0, stream>>>(
        P, vt, out, rs,
        SEQ, SEQ, SEQ, DIM,
        (long)SEQ * SEQ, (long)DIM * SEQ, (long)SEQ * DIM);
}